// Round 9
// baseline (505.600 us; speedup 1.0000x reference)
//
#include <hip/hip_runtime.h>

// ---------------------------------------------------------------------------
// MultiHeadAttention: B=2, T=2048, C=2048, H=16, D=128. fp32 in, fp32 out.
// Internals: bf16 MFMA, fp32 accum.
// R13: GEMMs 2-phase dbuf; attn ones-row PV. R14: 4 waves x 32 q-rows (reg
//      reuse). R15: XCD-locality remap. attn stuck ~135us: per-tile period
//      ~10k cy vs <=1k cy compute -> staged-load ARRIVAL LATENCY, depth-1
//      prefetch (issue-to-wait = 1 compute phase) cannot cover it.
// R16: depth-2 register prefetch: two named reg sets (static idx, rule #20),
//      pair-unrolled loop; issue-to-wait = 2 full tile periods (~8-10k cy).
// ---------------------------------------------------------------------------

typedef __attribute__((ext_vector_type(8))) short short8;
typedef __attribute__((ext_vector_type(4))) float floatx4;
typedef __attribute__((ext_vector_type(4))) unsigned int uint4v;

#define MFMA16(a, b, c) __builtin_amdgcn_mfma_f32_16x16x32_bf16(a, b, c, 0, 0, 0)

__device__ inline unsigned short f2bf(float f) {
    union { float f; unsigned int i; } v; v.f = f;
    unsigned int r = v.i + 0x7fff + ((v.i >> 16) & 1);   // round-nearest-even
    return (unsigned short)(r >> 16);
}

// async 16B global->LDS (m97). Per-lane lds ptrs must be base + lane*16.
__device__ inline void gl2lds16(const unsigned short* g, unsigned short* l) {
    __builtin_amdgcn_global_load_lds(
        (const __attribute__((address_space(1))) unsigned int*)g,
        (__attribute__((address_space(3))) unsigned int*)l, 16, 0, 0);
}

// workgroup barrier that does NOT drain vmcnt: LDS ordering only.
__device__ __forceinline__ void bar_lds_only() {
    asm volatile("s_waitcnt lgkmcnt(0)" ::: "memory");
    __builtin_amdgcn_sched_barrier(0);
    __builtin_amdgcn_s_barrier();
    __builtin_amdgcn_sched_barrier(0);
}

// ---------------- fp32 -> bf16 bulk convert (8 elems/thread) -----------------
__global__ __launch_bounds__(256) void cvt_k(const float* __restrict__ in,
                                             unsigned short* __restrict__ out, int n) {
    int i = (blockIdx.x * 256 + threadIdx.x) * 8;
    if (i + 7 < n) {
        float4 v0 = *(const float4*)(&in[i]);
        float4 v1 = *(const float4*)(&in[i + 4]);
        ushort4 o0, o1;
        o0.x = f2bf(v0.x); o0.y = f2bf(v0.y); o0.z = f2bf(v0.z); o0.w = f2bf(v0.w);
        o1.x = f2bf(v1.x); o1.y = f2bf(v1.y); o1.z = f2bf(v1.z); o1.w = f2bf(v1.w);
        *(ushort4*)(&out[i])     = o0;
        *(ushort4*)(&out[i + 4]) = o1;
    } else {
        for (int j = i; j < n; j++) out[j] = f2bf(in[j]);
    }
}

// ---------- fused fp32 transpose+cvt: in[R][Cc] f32 -> out[Cc][R] bf16 -------
__global__ __launch_bounds__(256) void transpose_f2b_k(const float* __restrict__ in,
                                                       unsigned short* __restrict__ out,
                                                       int R, int Cc) {
    __shared__ unsigned short tile[32][33];
    int ct = blockIdx.x * 32;
    int rt = blockIdx.y * 32;
    int tx = threadIdx.x & 31;
    int ty = threadIdx.x >> 5;
#pragma unroll
    for (int i = 0; i < 32; i += 8)
        tile[ty + i][tx] = f2bf(in[(size_t)(rt + ty + i) * Cc + ct + tx]);
    __syncthreads();
#pragma unroll
    for (int i = 0; i < 32; i += 8)
        out[(size_t)(ct + ty + i) * R + rt + tx] = tile[tx][ty + i];
}

// ------------- per-head V transpose: qkv[b,t,2,h,:] -> VT[bh][d][t] ----------
__global__ __launch_bounds__(256) void transpose_v_k(const unsigned short* __restrict__ qkv,
                                                     unsigned short* __restrict__ VT) {
    __shared__ unsigned short tile[32][33];
    int t0 = blockIdx.x * 32;
    int d0 = blockIdx.y * 32;
    int bh = blockIdx.z;
    int b = bh >> 4, h = bh & 15;
    int tx = threadIdx.x & 31;
    int ty = threadIdx.x >> 5;
#pragma unroll
    for (int i = 0; i < 32; i += 8)
        tile[ty + i][tx] =
            qkv[((size_t)(b * 2048 + t0 + ty + i) * 3 + 2) * 2048 + h * 128 + d0 + tx];
    __syncthreads();
#pragma unroll
    for (int i = 0; i < 32; i += 8)
        VT[((size_t)bh * 128 + d0 + ty + i) * 2048 + t0 + tx] = tile[tx][ty + i];
}

// ---------------- RoPE in place on q/k parts of qkv (fp32 cos/sin) -----------
__global__ __launch_bounds__(256) void rotary_k(unsigned short* qkv,
                                                const float* __restrict__ cosT,
                                                const float* __restrict__ sinT) {
    int idx = blockIdx.x * 256 + threadIdx.x;
    int d    = idx & 63;
    int h    = (idx >> 6) & 15;
    int part = (idx >> 10) & 1;
    int t    = (idx >> 11) & 2047;
    int b    = idx >> 22;
    size_t base = ((size_t)(b * 2048 + t) * 3 + part) * 2048 + h * 128;
    float c = cosT[t * 64 + d];
    float s = sinT[t * 64 + d];
    union { unsigned int i; float f; } u1, u2;
    u1.i = ((unsigned int)qkv[base + d]) << 16;
    u2.i = ((unsigned int)qkv[base + d + 64]) << 16;
    float x1 = u1.f, x2 = u2.f;
    qkv[base + d]      = f2bf(x1 * c - x2 * s);
    qkv[base + d + 64] = f2bf(x2 * c + x1 * s);
}

// ---- GEMM: C[M,N] = A[M,K](bf16) * Bt[N,K]^T(bf16), 2-phase dbuf staging ----
template <bool OUTF32>
__global__ __launch_bounds__(256) void gemm_bt(const unsigned short* __restrict__ A, long lda,
                                               const unsigned short* __restrict__ Bt,
                                               void* __restrict__ Co, long ldc,
                                               int M, int N, int K) {
    __shared__ unsigned short a_lds[2][128 * 32];   // unpadded: lane-contiguous DMA
    __shared__ unsigned short b_lds[2][128 * 32];
    int m0 = blockIdx.y * 128, n0 = blockIdx.x * 128;
    int tid = threadIdx.x;
    int lane = tid & 63, w = tid >> 6;
    int wm = (w >> 1) * 64, wn = (w & 1) * 64;
    int lr = lane & 15, quad = lane >> 4, lk = quad * 8;

    floatx4 acc[4][4];
    floatx4 zero4 = {0.f, 0.f, 0.f, 0.f};
#pragma unroll
    for (int i = 0; i < 4; i++)
#pragma unroll
        for (int j = 0; j < 4; j++) acc[i][j] = zero4;

    auto stage = [&](int k0, int buf) {
#pragma unroll
        for (int i = 0; i < 2; i++) {
            int c = w * 128 + i * 64 + lane;
            int row = c >> 2, seg = (c & 3) * 8;
            gl2lds16(&A[(size_t)(m0 + row) * lda + k0 + seg], &a_lds[buf][c * 8]);
            gl2lds16(&Bt[(size_t)(n0 + row) * K + k0 + seg], &b_lds[buf][c * 8]);
        }
    };

    int nt = K >> 5;
    stage(0, 0);
    __syncthreads();                          // buf0 ready
    for (int t = 0; t < nt; t++) {
        int buf = t & 1;
        if (t + 1 < nt) stage((t + 1) * 32, buf ^ 1);   // flies under MFMA(t)
        short8 af[4], bfr[4];
#pragma unroll
        for (int i = 0; i < 4; i++)
            af[i] = *(const short8*)(&a_lds[buf][(wm + i * 16 + lr) * 32 + lk]);
#pragma unroll
        for (int j = 0; j < 4; j++)
            bfr[j] = *(const short8*)(&b_lds[buf][(wn + j * 16 + lr) * 32 + lk]);
#pragma unroll
        for (int i = 0; i < 4; i++)
#pragma unroll
            for (int j = 0; j < 4; j++)
                acc[i][j] = MFMA16(af[i], bfr[j], acc[i][j]);
        __syncthreads();                      // drains vmcnt -> buf^1 ready
    }
#pragma unroll
    for (int i = 0; i < 4; i++)
#pragma unroll
        for (int j = 0; j < 4; j++)
#pragma unroll
            for (int r = 0; r < 4; r++) {
                int row = m0 + wm + i * 16 + quad * 4 + r;
                int col = n0 + wn + j * 16 + lr;
                if (OUTF32)
                    ((float*)Co)[(size_t)row * ldc + col] = acc[i][j][r];
                else
                    ((unsigned short*)Co)[(size_t)row * ldc + col] = f2bf(acc[i][j][r]);
            }
}

// ---------------------------------------------------------------------------
// attention core: TWO 16-q-row groups (A: rows qrow0.., B: rows qrow0+16..)
// vs one 64-key staged tile. Every kb/vb LDS read feeds both groups' MFMAs.
// K LDS swizzle: chunk' = chunk ^ (key&15). V: chunk ^ (d&7). P rows [72].
// l comes from PV MFMA vs the ones-row (V^T row 128) — no rsum shuffles.
// ---------------------------------------------------------------------------
__device__ __forceinline__ void attn_core_pair(
        const short8 (&qfA)[4], const short8 (&qfB)[4],
        floatx4 (&oA)[8], floatx4 (&oB)[8], floatx4& olA, floatx4& olB,
        float (&mA)[4], float (&mB)[4],
        const unsigned short* kb_lds, const unsigned short* vb_lds,
        unsigned short* p_w,
        int qrow0, int tk0, int lr, int quad, int lk) {
    floatx4 zero4 = {0.f, 0.f, 0.f, 0.f};
    const float scale = 0.08838834764831845f;

    floatx4 sA[4], sB[4];
#pragma unroll
    for (int n = 0; n < 4; n++) {
        sA[n] = zero4; sB[n] = zero4;
#pragma unroll
        for (int c = 0; c < 4; c++) {
            short8 kb = *(const short8*)(
                &kb_lds[(n * 16 + lr) * 128 + (((c * 4 + quad) ^ lr) * 8)]);
            sA[n] = MFMA16(qfA[c], kb, sA[n]);
            sB[n] = MFMA16(qfB[c], kb, sB[n]);
        }
    }

    float rmaxA[4], rmaxB[4];
#pragma unroll
    for (int r = 0; r < 4; r++) {
        int tqA = qrow0 + quad * 4 + r;
        int tqB = tqA + 16;
        float mxA = -1e30f, mxB = -1e30f;
#pragma unroll
        for (int n = 0; n < 4; n++) {
            int tk = tk0 + n * 16 + lr;
            float svA = sA[n][r] * scale;
            float svB = sB[n][r] * scale;
            svA = (tk > tqA) ? -1e30f : svA;
            svB = (tk > tqB) ? -1e30f : svB;
            sA[n][r] = svA; sB[n][r] = svB;
            mxA = fmaxf(mxA, svA); mxB = fmaxf(mxB, svB);
        }
        rmaxA[r] = mxA; rmaxB[r] = mxB;
    }
#pragma unroll
    for (int off = 1; off < 16; off <<= 1)
#pragma unroll
        for (int r = 0; r < 4; r++) {
            rmaxA[r] = fmaxf(rmaxA[r], __shfl_xor(rmaxA[r], off, 64));
            rmaxB[r] = fmaxf(rmaxB[r], __shfl_xor(rmaxB[r], off, 64));
        }

    float alphaA[4], alphaB[4];
#pragma unroll
    for (int r = 0; r < 4; r++) {
        float mnA = fmaxf(mA[r], rmaxA[r]);
        float mnB = fmaxf(mB[r], rmaxB[r]);
        alphaA[r] = __expf(mA[r] - mnA); mA[r] = mnA;
        alphaB[r] = __expf(mB[r] - mnB); mB[r] = mnB;
    }
#pragma unroll
    for (int n = 0; n < 4; n++)
#pragma unroll
        for (int r = 0; r < 4; r++) {
            float pA = __expf(sA[n][r] - mA[r]);
            float pB = __expf(sB[n][r] - mB[r]);
            p_w[(quad * 4 + r) * 72 + n * 16 + lr] = f2bf(pA);
            p_w[(16 + quad * 4 + r) * 72 + n * 16 + lr] = f2bf(pB);
        }

#pragma unroll
    for (int dt = 0; dt < 8; dt++)
#pragma unroll
        for (int r = 0; r < 4; r++) {
            oA[dt][r] *= alphaA[r];
            oB[dt][r] *= alphaB[r];
        }
#pragma unroll
    for (int r = 0; r < 4; r++) { olA[r] *= alphaA[r]; olB[r] *= alphaB[r]; }

    short8 paA[2], paB[2];
#pragma unroll
    for (int kc = 0; kc < 2; kc++) {
        paA[kc] = *(const short8*)(&p_w[lr * 72 + kc * 32 + lk]);
        paB[kc] = *(const short8*)(&p_w[(16 + lr) * 72 + kc * 32 + lk]);
    }
#pragma unroll
    for (int dt = 0; dt < 8; dt++) {
#pragma unroll
        for (int kc = 0; kc < 2; kc++) {
            short8 vb = *(const short8*)(
                &vb_lds[(dt * 16 + lr) * 64 + (((kc * 4 + quad) ^ (lr & 7)) * 8)]);
            oA[dt] = MFMA16(paA[kc], vb, oA[dt]);
            oB[dt] = MFMA16(paB[kc], vb, oB[dt]);
        }
    }
#pragma unroll
    for (int kc = 0; kc < 2; kc++) {
        short8 vb1 = *(const short8*)(&vb_lds[128 * 64 + (kc * 4 + quad) * 8]);
        olA = MFMA16(paA[kc], vb1, olA);
        olB = MFMA16(paB[kc], vb1, olB);
    }
}

// ------ flash attention: 128 q-rows/block, 4 waves x 32 rows, 64-key tiles --
// R15: 1-D grid 512; each XCD owns 4 bh. R16: depth-2 reg prefetch (two named
// sets, pair-unrolled), issue-to-wait = 2 tile periods.
__global__ __launch_bounds__(256, 2) void attn_fast(unsigned short* qkv,
                                                    const unsigned short* __restrict__ VT) {
    const int T = 2048, Cc = 2048, Dd = 128;
    int id = blockIdx.x;
    int xcd = id & 7, slot = id >> 3;          // slot in [0,64)
    int bh = xcd * 4 + (slot >> 4);
    int s = slot & 15;
    int qt = (s & 1) ? (s >> 1) : (15 - (s >> 1));   // balanced heavy+light
    int b = bh >> 4, h = bh & 15;
    int tid = threadIdx.x, lane = tid & 63, w = tid >> 6;   // w in [0,4)
    int lr = lane & 15, quad = lane >> 4, lk = quad * 8;
    int t0 = qt * 128;
    int wrow = t0 + w * 32;                    // this wave's first q-row

    __shared__ __align__(16) unsigned short k_lds[64 * 128];    // [key][d] swz
    __shared__ __align__(16) unsigned short v_lds[129 * 64];    // [d][key] swz + ones
    __shared__ __align__(16) unsigned short p_lds[4][32][72];   // per-wave P

    if (tid < 64) v_lds[128 * 64 + tid] = 0x3F80;   // bf16 1.0 ones-row

    short8 qfA[4], qfB[4];
    {
        size_t qrA = (size_t)(b * T + wrow + lr) * 3 * Cc + h * Dd;
        size_t qrB = (size_t)(b * T + wrow + 16 + lr) * 3 * Cc + h * Dd;
#pragma unroll
        for (int c = 0; c < 4; c++) {
            qfA[c] = *(const short8*)(&qkv[qrA + c * 32 + lk]);
            qfB[c] = *(const short8*)(&qkv[qrB + c * 32 + lk]);
        }
    }

    floatx4 oA[8], oB[8];
    floatx4 zero4 = {0.f, 0.f, 0.f, 0.f};
#pragma unroll
    for (int i = 0; i < 8; i++) { oA[i] = zero4; oB[i] = zero4; }
    floatx4 olA = zero4, olB = zero4;
    float mA[4], mB[4];
#pragma unroll
    for (int r = 0; r < 4; r++) { mA[r] = -1e30f; mB[r] = -1e30f; }

    // staging geometry (per thread: 4 K chunks + 4 V chunks of 16B)
    int krow[4], kslot[4], vrow[4], vslot[4];
#pragma unroll
    for (int i = 0; i < 4; i++) {
        int c = i * 256 + tid;
        krow[i] = c >> 4; kslot[i] = c & 15;       // K: 64 rows x 16 chunks
        vrow[i] = c >> 3; vslot[i] = c & 7;        // V: 128 rows x 8 chunks
    }
    // depth-2 prefetch: two NAMED register sets (static indexing, rule #20)
    uint4v k0r[4], v0r[4], k1r[4], v1r[4];
    auto gload0 = [&](int kt) {
        int tk0 = kt * 64;
#pragma unroll
        for (int i = 0; i < 4; i++) {
            k0r[i] = *(const uint4v*)(
                &qkv[((size_t)(b * T + tk0 + krow[i]) * 3 + 1) * Cc + h * Dd + kslot[i] * 8]);
            v0r[i] = *(const uint4v*)(
                &VT[((size_t)bh * Dd + vrow[i]) * T + tk0 + vslot[i] * 8]);
        }
    };
    auto gload1 = [&](int kt) {
        int tk0 = kt * 64;
#pragma unroll
        for (int i = 0; i < 4; i++) {
            k1r[i] = *(const uint4v*)(
                &qkv[((size_t)(b * T + tk0 + krow[i]) * 3 + 1) * Cc + h * Dd + kslot[i] * 8]);
            v1r[i] = *(const uint4v*)(
                &VT[((size_t)bh * Dd + vrow[i]) * T + tk0 + vslot[i] * 8]);
        }
    };
    auto lwrite0 = [&]() {
#pragma unroll
        for (int i = 0; i < 4; i++) {
            *(uint4v*)(&k_lds[krow[i] * 128 + ((kslot[i] ^ (krow[i] & 15)) * 8)]) = k0r[i];
            *(uint4v*)(&v_lds[vrow[i] * 64 + ((vslot[i] ^ (vrow[i] & 7)) * 8)]) = v0r[i];
        }
    };
    auto lwrite1 = [&]() {
#pragma unroll
        for (int i = 0; i < 4; i++) {
            *(uint4v*)(&k_lds[krow[i] * 128 + ((kslot[i] ^ (krow[i] & 15)) * 8)]) = k1r[i];
            *(uint4v*)(&v_lds[vrow[i] * 64 + ((vslot[i] ^ (vrow[i] & 7)) * 8)]) = v1r[i];
        }
    };

    int nkt = 2 * qt + 2;                          // always even, >= 2
    gload0(0);
    gload1(1);

    for (int kt = 0; kt < nkt; kt += 2) {
        // ---- tile kt (set 0) ----
        lwrite0();                                 // waits set0 (issued kt-2)
        bar_lds_only();                            // LDS tile ready (no vm drain)
        if (kt + 2 < nkt) gload0(kt + 2);          // 2 tile periods in flight
        {
            int tk0 = kt * 64;
            if (tk0 <= wrow + 31)
                attn_core_pair(qfA, qfB, oA, oB, olA, olB, mA, mB,
                               k_lds, v_lds, &p_lds[w][0][0], wrow, tk0, lr, quad, lk);
        }
        bar_lds_only();                            // all reads of tile kt done
        // ---- tile kt+1 (set 1) ----
        lwrite1();                                 // waits set1 (issued kt-1)
        bar_lds_only();
        if (kt + 3 < nkt) gload1(kt + 3);
        {
            int tk0 = (kt + 1) * 64;
            if (tk0 <= wrow + 31)
                attn_core_pair(qfA, qfB, oA, oB, olA, olB, mA, mB,
                               k_lds, v_lds, &p_lds[w][0][0], wrow, tk0, lr, quad, lk);
        }
        bar_lds_only();
    }

    // epilogue: O over q slots -> qkv[b, t, 0, h, d]
#pragma unroll
    for (int dt = 0; dt < 8; dt++)
#pragma unroll
        for (int r = 0; r < 4; r++) {
            int col = dt * 16 + lr;
            int rowA = wrow + quad * 4 + r;
            int rowB = rowA + 16;
            qkv[(size_t)(b * T + rowA) * 3 * Cc + h * Dd + col] =
                f2bf(oA[dt][r] * (1.0f / olA[r]));
            qkv[(size_t)(b * T + rowB) * 3 * Cc + h * Dd + col] =
                f2bf(oB[dt][r] * (1.0f / olB[r]));
        }
}

// ---------------------------------------------------------------------------
extern "C" void kernel_launch(void* const* d_in, const int* in_sizes, int n_in,
                              void* d_out, int out_size, void* d_ws, size_t ws_size,
                              hipStream_t stream) {
    const float* x    = (const float*)d_in[0];
    const float* wqkv = (const float*)d_in[1];
    const float* wout = (const float*)d_in[2];
    const float* cosT = (const float*)d_in[3];
    const float* sinT = (const float*)d_in[4];
    float* out = (float*)d_out;

    unsigned short* qkv = (unsigned short*)d_ws;          // 48 MiB
    const size_t QKV = 25165824, XBF = 8388608;
    unsigned short* xbf = qkv + QKV;                      // 16 MiB; VT overlays after gemm1
    unsigned short* wTq = xbf + XBF;                      // 24 MiB; wTo overlays after gemm1
    unsigned short* VT  = xbf;
    unsigned short* wTo = wTq;

    cvt_k<<<4096, 256, 0, stream>>>(x, xbf, 8388608);
    transpose_f2b_k<<<dim3(192, 64), 256, 0, stream>>>(wqkv, wTq, 2048, 6144);
    gemm_bt<false><<<dim3(48, 32), 256, 0, stream>>>(xbf, 2048, wTq, qkv, 6144,
                                                     4096, 6144, 2048);
    rotary_k<<<32768, 256, 0, stream>>>(qkv, cosT, sinT);
    transpose_f2b_k<<<dim3(64, 64), 256, 0, stream>>>(wout, wTo, 2048, 2048);
    transpose_v_k<<<dim3(64, 4, 32), 256, 0, stream>>>(qkv, VT);
    attn_fast<<<512, 256, 0, stream>>>(qkv, VT);
    gemm_bt<true><<<dim3(16, 32), 256, 0, stream>>>(qkv, 6144, wTo, out, 2048,
                                                    4096, 2048, 2048);
}

// Round 11
// 438.960 us; speedup vs baseline: 1.1518x; 1.1518x over previous
//
#include <hip/hip_runtime.h>

// ---------------------------------------------------------------------------
// MultiHeadAttention: B=2, T=2048, C=2048, H=16, D=128. fp32 in, fp32 out.
// Internals: bf16 MFMA, fp32 accum.
// R13: GEMMs 2-phase dbuf; attn ones-row PV. R14: 4 waves x 32 q-rows (best,
//      448.8us). R15: XCD remap (neutral). R16: depth-2 prefetch -> VGPR
//      spill, REVERTED. R17: V-transpose fused into gemm1 epilogue (VT in
//      d_out scratch); container infra failure. R18: resubmit R17 with
//      rule-#20 cleanup (no runtime-indexed LDS pointer arrays).
// ---------------------------------------------------------------------------

typedef __attribute__((ext_vector_type(8))) short short8;
typedef __attribute__((ext_vector_type(4))) float floatx4;
typedef __attribute__((ext_vector_type(4))) unsigned int uint4v;

#define MFMA16(a, b, c) __builtin_amdgcn_mfma_f32_16x16x32_bf16(a, b, c, 0, 0, 0)

__device__ inline unsigned short f2bf(float f) {
    union { float f; unsigned int i; } v; v.f = f;
    unsigned int r = v.i + 0x7fff + ((v.i >> 16) & 1);   // round-nearest-even
    return (unsigned short)(r >> 16);
}

// async 16B global->LDS (m97). Per-lane lds ptrs must be base + lane*16.
__device__ inline void gl2lds16(const unsigned short* g, unsigned short* l) {
    __builtin_amdgcn_global_load_lds(
        (const __attribute__((address_space(1))) unsigned int*)g,
        (__attribute__((address_space(3))) unsigned int*)l, 16, 0, 0);
}

// workgroup barrier that does NOT drain vmcnt: LDS ordering only.
__device__ __forceinline__ void bar_lds_only() {
    asm volatile("s_waitcnt lgkmcnt(0)" ::: "memory");
    __builtin_amdgcn_sched_barrier(0);
    __builtin_amdgcn_s_barrier();
    __builtin_amdgcn_sched_barrier(0);
}

// ---------------- fp32 -> bf16 bulk convert (8 elems/thread) -----------------
__global__ __launch_bounds__(256) void cvt_k(const float* __restrict__ in,
                                             unsigned short* __restrict__ out, int n) {
    int i = (blockIdx.x * 256 + threadIdx.x) * 8;
    if (i + 7 < n) {
        float4 v0 = *(const float4*)(&in[i]);
        float4 v1 = *(const float4*)(&in[i + 4]);
        ushort4 o0, o1;
        o0.x = f2bf(v0.x); o0.y = f2bf(v0.y); o0.z = f2bf(v0.z); o0.w = f2bf(v0.w);
        o1.x = f2bf(v1.x); o1.y = f2bf(v1.y); o1.z = f2bf(v1.z); o1.w = f2bf(v1.w);
        *(ushort4*)(&out[i])     = o0;
        *(ushort4*)(&out[i + 4]) = o1;
    } else {
        for (int j = i; j < n; j++) out[j] = f2bf(in[j]);
    }
}

// ---------- fused fp32 transpose+cvt: in[R][Cc] f32 -> out[Cc][R] bf16 -------
__global__ __launch_bounds__(256) void transpose_f2b_k(const float* __restrict__ in,
                                                       unsigned short* __restrict__ out,
                                                       int R, int Cc) {
    __shared__ unsigned short tile[32][33];
    int ct = blockIdx.x * 32;
    int rt = blockIdx.y * 32;
    int tx = threadIdx.x & 31;
    int ty = threadIdx.x >> 5;
#pragma unroll
    for (int i = 0; i < 32; i += 8)
        tile[ty + i][tx] = f2bf(in[(size_t)(rt + ty + i) * Cc + ct + tx]);
    __syncthreads();
#pragma unroll
    for (int i = 0; i < 32; i += 8)
        out[(size_t)(ct + ty + i) * R + rt + tx] = tile[tx][ty + i];
}

// ---------------- RoPE in place on q/k parts of qkv (fp32 cos/sin) -----------
__global__ __launch_bounds__(256) void rotary_k(unsigned short* qkv,
                                                const float* __restrict__ cosT,
                                                const float* __restrict__ sinT) {
    int idx = blockIdx.x * 256 + threadIdx.x;
    int d    = idx & 63;
    int h    = (idx >> 6) & 15;
    int part = (idx >> 10) & 1;
    int t    = (idx >> 11) & 2047;
    int b    = idx >> 22;
    size_t base = ((size_t)(b * 2048 + t) * 3 + part) * 2048 + h * 128;
    float c = cosT[t * 64 + d];
    float s = sinT[t * 64 + d];
    union { unsigned int i; float f; } u1, u2;
    u1.i = ((unsigned int)qkv[base + d]) << 16;
    u2.i = ((unsigned int)qkv[base + d + 64]) << 16;
    float x1 = u1.f, x2 = u2.f;
    qkv[base + d]      = f2bf(x1 * c - x2 * s);
    qkv[base + d + 64] = f2bf(x2 * c + x1 * s);
}

// ---- GEMM: C[M,N] = A[M,K](bf16) * Bt[N,K]^T(bf16), 2-phase dbuf staging ----
// FUSEV (gemm1 only): tiles with n0>=4096 are V[b,t,h,d]; write them
// TRANSPOSED to VTout[bh][d][t] via swizzled LDS stage, skip the qkv write.
template <bool OUTF32, bool FUSEV>
__global__ __launch_bounds__(256) void gemm_bt(const unsigned short* __restrict__ A, long lda,
                                               const unsigned short* __restrict__ Bt,
                                               void* __restrict__ Co, long ldc,
                                               int M, int N, int K,
                                               unsigned short* __restrict__ VTout) {
    // 32 KB shared: staging (2x A + 2x B K-tiles); re-used as c_stage in epilogue
    __shared__ __align__(16) unsigned short smem[16384];
    int m0 = blockIdx.y * 128, n0 = blockIdx.x * 128;
    int tid = threadIdx.x;
    int lane = tid & 63, w = tid >> 6;
    int wm = (w >> 1) * 64, wn = (w & 1) * 64;
    int lr = lane & 15, quad = lane >> 4, lk = quad * 8;

    floatx4 acc[4][4];
    floatx4 zero4 = {0.f, 0.f, 0.f, 0.f};
#pragma unroll
    for (int i = 0; i < 4; i++)
#pragma unroll
        for (int j = 0; j < 4; j++) acc[i][j] = zero4;

    auto stage = [&](int k0, int buf) {
        unsigned short* a_l = smem + buf * 4096;
        unsigned short* b_l = smem + 8192 + buf * 4096;
#pragma unroll
        for (int i = 0; i < 2; i++) {
            int c = w * 128 + i * 64 + lane;
            int row = c >> 2, seg = (c & 3) * 8;
            gl2lds16(&A[(size_t)(m0 + row) * lda + k0 + seg], &a_l[c * 8]);
            gl2lds16(&Bt[(size_t)(n0 + row) * K + k0 + seg], &b_l[c * 8]);
        }
    };

    int nt = K >> 5;
    stage(0, 0);
    __syncthreads();                          // buf0 ready
    for (int t = 0; t < nt; t++) {
        int buf = t & 1;
        if (t + 1 < nt) stage((t + 1) * 32, buf ^ 1);   // flies under MFMA(t)
        const unsigned short* a_l = smem + buf * 4096;
        const unsigned short* b_l = smem + 8192 + buf * 4096;
        short8 af[4], bfr[4];
#pragma unroll
        for (int i = 0; i < 4; i++)
            af[i] = *(const short8*)(&a_l[(wm + i * 16 + lr) * 32 + lk]);
#pragma unroll
        for (int j = 0; j < 4; j++)
            bfr[j] = *(const short8*)(&b_l[(wn + j * 16 + lr) * 32 + lk]);
#pragma unroll
        for (int i = 0; i < 4; i++)
#pragma unroll
            for (int j = 0; j < 4; j++)
                acc[i][j] = MFMA16(af[i], bfr[j], acc[i][j]);
        __syncthreads();                      // drains vmcnt -> buf^1 ready
    }

    if (FUSEV && n0 >= 4096) {
        // ---- V tile: transpose via c_stage (aliases smem, dead after loop) --
        // element (row,col) stored at smem[col*128 + (row ^ 8*(col&15))]
        int h = (n0 >> 7) & 15;
        int bb = m0 >> 11, t0b = m0 & 2047;
        int bh = bb * 16 + h;
        __syncthreads();                      // staging reads fully done
#pragma unroll
        for (int i = 0; i < 4; i++)
#pragma unroll
            for (int j = 0; j < 4; j++) {
                int col = wn + j * 16 + lr;
                int rowb = wm + i * 16 + quad * 4;
                int addr = col * 128 + (rowb ^ ((col & 15) << 3));
                ushort4 v;
                v.x = f2bf(acc[i][j][0]); v.y = f2bf(acc[i][j][1]);
                v.z = f2bf(acc[i][j][2]); v.w = f2bf(acc[i][j][3]);
                *(ushort4*)(&smem[addr]) = v;
            }
        __syncthreads();
#pragma unroll
        for (int p = 0; p < 8; p++) {
            int e = (p * 256 + tid) * 8;           // 16384 elems / 256 thr
            int cd = e >> 7, ro = e & 127;         // cd = d (tile col), ro = t off
            short8 v = *(const short8*)(&smem[cd * 128 + (ro ^ ((cd & 15) << 3))]);
            *(short8*)(&VTout[((size_t)bh * 128 + cd) * 2048 + t0b + ro]) = v;
        }
        return;
    }

#pragma unroll
    for (int i = 0; i < 4; i++)
#pragma unroll
        for (int j = 0; j < 4; j++)
#pragma unroll
            for (int r = 0; r < 4; r++) {
                int row = m0 + wm + i * 16 + quad * 4 + r;
                int col = n0 + wn + j * 16 + lr;
                if (OUTF32)
                    ((float*)Co)[(size_t)row * ldc + col] = acc[i][j][r];
                else
                    ((unsigned short*)Co)[(size_t)row * ldc + col] = f2bf(acc[i][j][r]);
            }
}

// ---------------------------------------------------------------------------
// attention core: TWO 16-q-row groups (A: rows qrow0.., B: rows qrow0+16..)
// vs one 64-key staged tile. Every kb/vb LDS read feeds both groups' MFMAs.
// K LDS swizzle: chunk' = chunk ^ (key&15). V: chunk ^ (d&7). P rows [72].
// l comes from PV MFMA vs the ones-row (V^T row 128) — no rsum shuffles.
// ---------------------------------------------------------------------------
__device__ __forceinline__ void attn_core_pair(
        const short8 (&qfA)[4], const short8 (&qfB)[4],
        floatx4 (&oA)[8], floatx4 (&oB)[8], floatx4& olA, floatx4& olB,
        float (&mA)[4], float (&mB)[4],
        const unsigned short* kb_lds, const unsigned short* vb_lds,
        unsigned short* p_w,
        int qrow0, int tk0, int lr, int quad, int lk) {
    floatx4 zero4 = {0.f, 0.f, 0.f, 0.f};
    const float scale = 0.08838834764831845f;

    floatx4 sA[4], sB[4];
#pragma unroll
    for (int n = 0; n < 4; n++) {
        sA[n] = zero4; sB[n] = zero4;
#pragma unroll
        for (int c = 0; c < 4; c++) {
            short8 kb = *(const short8*)(
                &kb_lds[(n * 16 + lr) * 128 + (((c * 4 + quad) ^ lr) * 8)]);
            sA[n] = MFMA16(qfA[c], kb, sA[n]);
            sB[n] = MFMA16(qfB[c], kb, sB[n]);
        }
    }

    float rmaxA[4], rmaxB[4];
#pragma unroll
    for (int r = 0; r < 4; r++) {
        int tqA = qrow0 + quad * 4 + r;
        int tqB = tqA + 16;
        float mxA = -1e30f, mxB = -1e30f;
#pragma unroll
        for (int n = 0; n < 4; n++) {
            int tk = tk0 + n * 16 + lr;
            float svA = sA[n][r] * scale;
            float svB = sB[n][r] * scale;
            svA = (tk > tqA) ? -1e30f : svA;
            svB = (tk > tqB) ? -1e30f : svB;
            sA[n][r] = svA; sB[n][r] = svB;
            mxA = fmaxf(mxA, svA); mxB = fmaxf(mxB, svB);
        }
        rmaxA[r] = mxA; rmaxB[r] = mxB;
    }
#pragma unroll
    for (int off = 1; off < 16; off <<= 1)
#pragma unroll
        for (int r = 0; r < 4; r++) {
            rmaxA[r] = fmaxf(rmaxA[r], __shfl_xor(rmaxA[r], off, 64));
            rmaxB[r] = fmaxf(rmaxB[r], __shfl_xor(rmaxB[r], off, 64));
        }

    float alphaA[4], alphaB[4];
#pragma unroll
    for (int r = 0; r < 4; r++) {
        float mnA = fmaxf(mA[r], rmaxA[r]);
        float mnB = fmaxf(mB[r], rmaxB[r]);
        alphaA[r] = __expf(mA[r] - mnA); mA[r] = mnA;
        alphaB[r] = __expf(mB[r] - mnB); mB[r] = mnB;
    }
#pragma unroll
    for (int n = 0; n < 4; n++)
#pragma unroll
        for (int r = 0; r < 4; r++) {
            float pA = __expf(sA[n][r] - mA[r]);
            float pB = __expf(sB[n][r] - mB[r]);
            p_w[(quad * 4 + r) * 72 + n * 16 + lr] = f2bf(pA);
            p_w[(16 + quad * 4 + r) * 72 + n * 16 + lr] = f2bf(pB);
        }

#pragma unroll
    for (int dt = 0; dt < 8; dt++)
#pragma unroll
        for (int r = 0; r < 4; r++) {
            oA[dt][r] *= alphaA[r];
            oB[dt][r] *= alphaB[r];
        }
#pragma unroll
    for (int r = 0; r < 4; r++) { olA[r] *= alphaA[r]; olB[r] *= alphaB[r]; }

    short8 paA[2], paB[2];
#pragma unroll
    for (int kc = 0; kc < 2; kc++) {
        paA[kc] = *(const short8*)(&p_w[lr * 72 + kc * 32 + lk]);
        paB[kc] = *(const short8*)(&p_w[(16 + lr) * 72 + kc * 32 + lk]);
    }
#pragma unroll
    for (int dt = 0; dt < 8; dt++) {
#pragma unroll
        for (int kc = 0; kc < 2; kc++) {
            short8 vb = *(const short8*)(
                &vb_lds[(dt * 16 + lr) * 64 + (((kc * 4 + quad) ^ (lr & 7)) * 8)]);
            oA[dt] = MFMA16(paA[kc], vb, oA[dt]);
            oB[dt] = MFMA16(paB[kc], vb, oB[dt]);
        }
    }
#pragma unroll
    for (int kc = 0; kc < 2; kc++) {
        short8 vb1 = *(const short8*)(&vb_lds[128 * 64 + (kc * 4 + quad) * 8]);
        olA = MFMA16(paA[kc], vb1, olA);
        olB = MFMA16(paB[kc], vb1, olB);
    }
}

// ------ flash attention: 128 q-rows/block, 4 waves x 32 rows, 64-key tiles --
// (R14 structure: depth-1 reg prefetch, lgkm-only barriers, balanced qt map)
__global__ __launch_bounds__(256, 2) void attn_fast(unsigned short* qkv,
                                                    const unsigned short* __restrict__ VT) {
    const int T = 2048, Cc = 2048, Dd = 128;
    int xx = blockIdx.x;
    int qt = (xx & 1) ? (xx >> 1) : (15 - (xx >> 1));   // balanced heavy+light
    int bh = blockIdx.y;
    int b = bh >> 4, h = bh & 15;
    int tid = threadIdx.x, lane = tid & 63, w = tid >> 6;   // w in [0,4)
    int lr = lane & 15, quad = lane >> 4, lk = quad * 8;
    int t0 = qt * 128;
    int wrow = t0 + w * 32;                    // this wave's first q-row

    __shared__ __align__(16) unsigned short k_lds[64 * 128];    // [key][d] swz
    __shared__ __align__(16) unsigned short v_lds[129 * 64];    // [d][key] swz + ones
    __shared__ __align__(16) unsigned short p_lds[4][32][72];   // per-wave P

    if (tid < 64) v_lds[128 * 64 + tid] = 0x3F80;   // bf16 1.0 ones-row

    short8 qfA[4], qfB[4];
    {
        size_t qrA = (size_t)(b * T + wrow + lr) * 3 * Cc + h * Dd;
        size_t qrB = (size_t)(b * T + wrow + 16 + lr) * 3 * Cc + h * Dd;
#pragma unroll
        for (int c = 0; c < 4; c++) {
            qfA[c] = *(const short8*)(&qkv[qrA + c * 32 + lk]);
            qfB[c] = *(const short8*)(&qkv[qrB + c * 32 + lk]);
        }
    }

    floatx4 oA[8], oB[8];
    floatx4 zero4 = {0.f, 0.f, 0.f, 0.f};
#pragma unroll
    for (int i = 0; i < 8; i++) { oA[i] = zero4; oB[i] = zero4; }
    floatx4 olA = zero4, olB = zero4;
    float mA[4], mB[4];
#pragma unroll
    for (int r = 0; r < 4; r++) { mA[r] = -1e30f; mB[r] = -1e30f; }

    // staging geometry (per thread: 4 K chunks + 4 V chunks of 16B)
    int krow[4], kslot[4], vrow[4], vslot[4];
#pragma unroll
    for (int i = 0; i < 4; i++) {
        int c = i * 256 + tid;
        krow[i] = c >> 4; kslot[i] = c & 15;       // K: 64 rows x 16 chunks
        vrow[i] = c >> 3; vslot[i] = c & 7;        // V: 128 rows x 8 chunks
    }
    uint4v kA[4], vA[4];
    auto gload = [&](int kt) {
        int tk0 = kt * 64;
#pragma unroll
        for (int i = 0; i < 4; i++) {
            kA[i] = *(const uint4v*)(
                &qkv[((size_t)(b * T + tk0 + krow[i]) * 3 + 1) * Cc + h * Dd + kslot[i] * 8]);
            vA[i] = *(const uint4v*)(
                &VT[((size_t)bh * Dd + vrow[i]) * T + tk0 + vslot[i] * 8]);
        }
    };
    auto lwrite = [&]() {
#pragma unroll
        for (int i = 0; i < 4; i++) {
            *(uint4v*)(&k_lds[krow[i] * 128 + ((kslot[i] ^ (krow[i] & 15)) * 8)]) = kA[i];
            *(uint4v*)(&v_lds[vrow[i] * 64 + ((vslot[i] ^ (vrow[i] & 7)) * 8)]) = vA[i];
        }
    };

    int nkt = 2 * qt + 2;
    gload(0);

    for (int kt = 0; kt < nkt; kt++) {
        lwrite();                                  // vmcnt waited by dependence
        bar_lds_only();                            // LDS tile ready (no vm drain)
        if (kt + 1 < nkt) gload(kt + 1);           // in flight across whole tile
        int tk0 = kt * 64;
        if (tk0 <= wrow + 31)                      // wave-uniform skip (grp B bound)
            attn_core_pair(qfA, qfB, oA, oB, olA, olB, mA, mB,
                           k_lds, v_lds, &p_lds[w][0][0], wrow, tk0, lr, quad, lk);
        bar_lds_only();                            // all reads of tile kt done
    }

    // epilogue: O over q slots -> qkv[b, t, 0, h, d]
#pragma unroll
    for (int dt = 0; dt < 8; dt++)
#pragma unroll
        for (int r = 0; r < 4; r++) {
            int col = dt * 16 + lr;
            int rowA = wrow + quad * 4 + r;
            int rowB = rowA + 16;
            qkv[(size_t)(b * T + rowA) * 3 * Cc + h * Dd + col] =
                f2bf(oA[dt][r] * (1.0f / olA[r]));
            qkv[(size_t)(b * T + rowB) * 3 * Cc + h * Dd + col] =
                f2bf(oB[dt][r] * (1.0f / olB[r]));
        }
}

// ---------------------------------------------------------------------------
extern "C" void kernel_launch(void* const* d_in, const int* in_sizes, int n_in,
                              void* d_out, int out_size, void* d_ws, size_t ws_size,
                              hipStream_t stream) {
    const float* x    = (const float*)d_in[0];
    const float* wqkv = (const float*)d_in[1];
    const float* wout = (const float*)d_in[2];
    const float* cosT = (const float*)d_in[3];
    const float* sinT = (const float*)d_in[4];
    float* out = (float*)d_out;

    unsigned short* qkv = (unsigned short*)d_ws;          // 48 MiB
    const size_t QKV = 25165824, XBF = 8388608;
    unsigned short* xbf = qkv + QKV;                      // 16 MiB (A input, live thru gemm1)
    unsigned short* wTq = xbf + XBF;                      // 24 MiB; wTo overlays after gemm1
    unsigned short* wTo = wTq;
    // VT lives in d_out scratch (16.8 MiB < 33.5 MiB): written by gemm1
    // epilogue, read by attn, then d_out overwritten by gemm2 (stream-ordered).
    unsigned short* VT  = (unsigned short*)d_out;

    cvt_k<<<4096, 256, 0, stream>>>(x, xbf, 8388608);
    transpose_f2b_k<<<dim3(192, 64), 256, 0, stream>>>(wqkv, wTq, 2048, 6144);
    gemm_bt<false, true><<<dim3(48, 32), 256, 0, stream>>>(xbf, 2048, wTq, qkv, 6144,
                                                           4096, 6144, 2048, VT);
    rotary_k<<<32768, 256, 0, stream>>>(qkv, cosT, sinT);
    transpose_f2b_k<<<dim3(64, 64), 256, 0, stream>>>(wout, wTo, 2048, 2048);
    attn_fast<<<dim3(16, 32), 256, 0, stream>>>(qkv, VT);
    gemm_bt<true, false><<<dim3(16, 32), 256, 0, stream>>>(qkv, 6144, wTo, out, 2048,
                                                           4096, 2048, 2048, nullptr);
}